// Round 1
// 1907.629 us; speedup vs baseline: 1.3099x; 1.3099x over previous
//
#include <hip/hip_runtime.h>

typedef __bf16 bf16;
typedef __bf16 bf16x8 __attribute__((ext_vector_type(8)));
typedef float  f32x16 __attribute__((ext_vector_type(16)));
typedef unsigned int u32;
typedef unsigned int u32x4 __attribute__((ext_vector_type(4)));

// ---------------- ws layout (bytes) ----------------
#define OFF_RW      0ull                 // rearranged weights, bf16 (12910592 B)
// h exchange: [layer2][buf2][group8][producer32][row32][col16] bf16 = 1 MB
#define OFF_HB      12910592ull
#define HB_BYTES    1048576ull
#define OFF_FLAG0   13959168ull          // 8 groups x 32 producer flags (u32)
#define OFF_FLAG1   13960192ull
#define OFF_DCTR    13961216ull          // device barrier counter (64 B)

// elem offsets into rW (bf16 elems); K-prefix {0,64,576,1088,1600,1616,2128,2640}
#define EO_W0   0
#define EO_U0   131072
#define EO_W1   1179648
#define EO_U1   2228224
#define EO_DW0  3276800
#define EO_DU0  3309568
#define EO_DW1  4358144
#define EO_DU1  5406720   // holds (dW1 + dU1) combined (dec1: x == h_init)

// LDS layout (dynamic 160 KB)
#define LDS_U0    0u
#define LDS_U1    65536u
#define LDS_WP0   131072u
#define LDS_WP1   147456u
#define LDS_TOTAL 163840

// ---------------- activations ----------------
__device__ __forceinline__ float fsig(float x) {
  x = fminf(fmaxf(x, -30.f), 30.f);
  float e = __builtin_amdgcn_exp2f(x * -1.4426950408889634f);
  return __builtin_amdgcn_rcpf(1.0f + e);
}
__device__ __forceinline__ float ftanh(float x) {
  x = fminf(fmaxf(x, -15.f), 15.f);
  float e = __builtin_amdgcn_exp2f(x * -2.8853900817779268f);
  return (1.0f - e) * __builtin_amdgcn_rcpf(1.0f + e);
}

// sc1 (agent-coherent / LLC) memory ops
#define HLOAD16(dst, addr) \
  asm volatile("global_load_dwordx4 %0, %1, off sc1" : "=v"(dst) : "v"(addr) : "memory")
#define HSTORE2(addr, val) \
  asm volatile("global_store_short %0, %1, off sc1" :: "v"(addr), "v"(val) : "memory")
#define HSTORE16(addr, val) \
  asm volatile("global_store_dwordx4 %0, %1, off sc1" :: "v"(addr), "v"(val) : "memory")
#define WAIT_VM(n) asm volatile("s_waitcnt vmcnt(" #n ")" ::: "memory")
#define WAIT_LGKM0() asm volatile("s_waitcnt lgkmcnt(0)" ::: "memory")
#define SCHED0() __builtin_amdgcn_sched_barrier(0)

typedef const __attribute__((address_space(1))) u32* as1_u32p;
typedef __attribute__((address_space(3))) u32* as3_u32p;
// global -> LDS direct (width 16B/lane), dest = uniform base + lane*16
#define GLL16(gsrc, ldsoff) \
  __builtin_amdgcn_global_load_lds((as1_u32p)(const void*)(gsrc), \
                                   (as3_u32p)(void*)(smem + (ldsoff)), 16, 0, 0)

// ---------------- main persistent kernel ----------------
// grid 256 wgs x 64 thr; wg -> (group g = blk&7 [32 batch rows], nc = blk>>3 [16 h-cols])
// Pipelined ticks t=1..129: L0 step t  +  L1 step t-1 (L1 trails by 1).
__global__ void __launch_bounds__(64, 1)
lstm_main(const float* __restrict__ inp,
          const float* __restrict__ eW0, const float* __restrict__ eU0, const float* __restrict__ eb0,
          const float* __restrict__ eW1, const float* __restrict__ eU1, const float* __restrict__ eb1,
          const float* __restrict__ dW0, const float* __restrict__ dU0, const float* __restrict__ db0,
          const float* __restrict__ dW1, const float* __restrict__ dU1, const float* __restrict__ db1,
          const float* __restrict__ fcW, const float* __restrict__ fcb,
          unsigned char* __restrict__ ws, float* __restrict__ out)
{
  extern __shared__ __align__(16) unsigned char smem[];

  const int wgid = blockIdx.x;
  const int g    = wgid & 7;
  const int nc   = wgid >> 3;
  const int lane = threadIdx.x;
  const int rowbase = g * 32;
  const int col32 = lane & 31;
  const int khalf = lane >> 5;
  const int half  = col32 >> 4;
  const int rowA  = rowbase + col32;

  const bf16* rW = reinterpret_cast<const bf16*>(ws + OFF_RW);
  bf16* hb  = reinterpret_cast<bf16*>(ws + OFF_HB);
  unsigned* flag0 = reinterpret_cast<unsigned*>(ws + OFF_FLAG0) + g * 32;
  unsigned* flag1 = reinterpret_cast<unsigned*>(ws + OFF_FLAG1) + g * 32;
  unsigned* dctr  = reinterpret_cast<unsigned*>(ws + OFF_DCTR);

  unsigned depoch = 0;
  auto dbarrier = [&]() {
    depoch++;
    WAIT_VM(0);
    if (lane == 0) __hip_atomic_fetch_add(dctr, 1u, __ATOMIC_RELAXED, __HIP_MEMORY_SCOPE_AGENT);
    const unsigned tgt = depoch * 256u;
    while (__hip_atomic_load(dctr, __ATOMIC_RELAXED, __HIP_MEMORY_SCOPE_AGENT) < tgt)
      __builtin_amdgcn_s_sleep(1);
  };

  // ================= inline prep: weights -> MFMA B-fragment order (sc1 stores) ====
  {
    const int Ks[8]    = {64, 512, 512, 512, 16, 512, 512, 512};
    const int pref[8]  = {0, 64, 576, 1088, 1600, 1616, 2128, 2640};
    const float* srcs[8] = {eW0, eU0, eW1, eU1, dW0, dU0, dW1, dU1};
    bf16* rWw = reinterpret_cast<bf16*>(ws + OFF_RW);
    for (int base = 0; base < 3152; base += 64) {
      if (base + lane < 3152) {
        unsigned uid = (unsigned)wgid * 3152u + (unsigned)(base + lane);
        int m = 0;
#pragma unroll
        for (int i = 1; i < 8; ++i) if (uid >= (unsigned)pref[i] * 256u) m = i;
        unsigned local = uid - (unsigned)pref[m] * 256u;
        const int K = Ks[m];
        const unsigned perNC   = (unsigned)K * 8u;
        const unsigned ncb     = local / perNC;
        const unsigned r0      = local % perNC;
        const unsigned perTile = perNC >> 1;
        const unsigned ntile   = r0 / perTile;
        const unsigned r1      = r0 % perTile;
        const unsigned kstep   = r1 >> 6;
        const unsigned ln      = r1 & 63u;
        const unsigned c32     = ln & 31u;
        const unsigned gate    = ntile * 2u + (c32 >> 4);
        const unsigned zcol    = gate * 512u + ncb * 16u + (c32 & 15u);
        const unsigned kb      = kstep * 16u + (ln >> 5) * 8u;
        const float* s = srcs[m];
        bf16x8 v;
#pragma unroll
        for (int j = 0; j < 8; ++j) {
          float vj = s[(size_t)(kb + j) * 2048u + zcol];
          if (m == 7) vj += dW1[(size_t)(kb + j) * 2048u + zcol];  // dec1 combined W+U
          v[j] = (bf16)vj;
        }
        u32x4 bits = __builtin_bit_cast(u32x4, v);
        HSTORE16(rWw + (size_t)uid * 8, bits);
      }
    }
  }
  dbarrier();
  __builtin_amdgcn_fence(__ATOMIC_ACQUIRE, "agent");  // one-time: purge stale L1/L2

  // bias registers (gate pair [i|f] -> a, [g|o] -> b)
  const int bcol = nc * 16 + (col32 & 15);
  const int bg_  = col32 >> 4;
  const float bE0a = eb0[bg_ * 512 + bcol], bE0b = eb0[(2 + bg_) * 512 + bcol];
  const float bE1a = eb1[bg_ * 512 + bcol], bE1b = eb1[(2 + bg_) * 512 + bcol];
  const float bD0a = db0[bg_ * 512 + bcol], bD0b = db0[(2 + bg_) * 512 + bcol];
  const float bD1a = db1[bg_ * 512 + bcol], bD1b = db1[(2 + bg_) * 512 + bcol];

  float c0[16], c1[16];
#pragma unroll
  for (int i = 0; i < 16; ++i) { c0[i] = 0.f; c1[i] = 0.f; }

  const bf16* rU0e = rW + EO_U0 + (size_t)nc * 32768;
  const bf16* rU1e = rW + EO_U1 + (size_t)nc * 32768;
  const bf16* rX0e = rW + EO_W0 + (size_t)nc * 4096;
  const bf16* rX1e = rW + EO_W1 + (size_t)nc * 32768;

  u32x4 hreg[16];

  auto load_lds = [&](const bf16* src, u32 off) {
#pragma unroll 8
    for (int i = 0; i < 64; ++i) {
      *reinterpret_cast<bf16x8*>(smem + off + (i * 64 + lane) * 16) =
        *reinterpret_cast<const bf16x8*>(src + (size_t)(i * 64 + lane) * 8);
    }
    __syncthreads();
  };

  // stage W1 batch b (8 k-slices, both gate tiles) -> LDS ping at ldsoff (16 KB)
  auto stageW = [&](int b, u32 ldsoff) {
    const char* src0 = (const char*)rX1e + (size_t)b * 8192 + lane * 16;           // bg0
    const char* src1 = (const char*)rX1e + 32768 + (size_t)b * 8192 + lane * 16;   // bg1
#pragma unroll
    for (int j = 0; j < 8; ++j) {
      GLL16(src0 + j * 1024, ldsoff + j * 1024);
      GLL16(src1 + j * 1024, ldsoff + 8192 + j * 1024);
    }
  };

  // fused batch: L0 rec (U0 from LDS) + L1 x (W1 from LDS ping), shared A-frags
  auto fbatch = [&](int b, u32 wp, f32x16& A0, f32x16& A1, f32x16& D0, f32x16& D1) {
#pragma unroll
    for (int i = 0; i < 8; ++i) {
      const int ks = b * 8 + i;
      bf16x8 af  = __builtin_bit_cast(bf16x8, hreg[(b & 1) * 8 + i]);
      bf16x8 bl0 = *reinterpret_cast<const bf16x8*>(smem + LDS_U0 + (ks * 64 + lane) * 16);
      bf16x8 bl1 = *reinterpret_cast<const bf16x8*>(smem + LDS_U0 + 32768 + (ks * 64 + lane) * 16);
      bf16x8 bw0 = *reinterpret_cast<const bf16x8*>(smem + wp + i * 1024 + lane * 16);
      bf16x8 bw1 = *reinterpret_cast<const bf16x8*>(smem + wp + 8192 + i * 1024 + lane * 16);
      A0 = __builtin_amdgcn_mfma_f32_32x32x16_bf16(af, bl0, A0, 0, 0, 0);
      A1 = __builtin_amdgcn_mfma_f32_32x32x16_bf16(af, bl1, A1, 0, 0, 0);
      D0 = __builtin_amdgcn_mfma_f32_32x32x16_bf16(af, bw0, D0, 0, 0, 0);
      D1 = __builtin_amdgcn_mfma_f32_32x32x16_bf16(af, bw1, D1, 0, 0, 0);
    }
  };

  // plain recurrent batch vs LDS U at uoff
  auto ubatch = [&](int b, u32 uoff, f32x16& A0, f32x16& A1) {
#pragma unroll
    for (int i = 0; i < 8; ++i) {
      const int ks = b * 8 + i;
      bf16x8 af  = __builtin_bit_cast(bf16x8, hreg[(b & 1) * 8 + i]);
      bf16x8 bl0 = *reinterpret_cast<const bf16x8*>(smem + uoff + (ks * 64 + lane) * 16);
      bf16x8 bl1 = *reinterpret_cast<const bf16x8*>(smem + uoff + 32768 + (ks * 64 + lane) * 16);
      A0 = __builtin_amdgcn_mfma_f32_32x32x16_bf16(af, bl0, A0, 0, 0, 0);
      A1 = __builtin_amdgcn_mfma_f32_32x32x16_bf16(af, bl1, A1, 0, 0, 0);
    }
  };

  // full h-block GEMM with its own pipelined loads (decoder steps)
  auto recgemm = [&](const char* hp, u32 uoff, f32x16& A0, f32x16& A1) {
#pragma unroll
    for (int i = 0; i < 16; ++i) HLOAD16(hreg[i], hp + i * 1024);
#pragma unroll
    for (int b = 0; b < 4; ++b) {
      if (b < 3) { WAIT_VM(8); } else { WAIT_VM(0); }
      SCHED0();
      ubatch(b, uoff, A0, A1);
      if (b < 2) {
#pragma unroll
        for (int i = 0; i < 8; ++i) HLOAD16(hreg[(b & 1) * 8 + i], hp + (16 + b * 8 + i) * 1024);
      }
    }
  };

  // gates: A0=[i|f] cols, A1=[g|o] cols; partner via shfl_xor 16; h slice -> hdst
  auto gates = [&](f32x16& A0, f32x16& A1, float* cc, bf16* hdst) {
#pragma unroll
    for (int r = 0; r < 16; ++r) {
      float v0 = A0[r], v1 = A1[r];
      float v0x = __shfl_xor(v0, 16, 64);
      float v1x = __shfl_xor(v1, 16, 64);
      float iv = half ? v0x : v0;
      float fv = half ? v0  : v0x;
      float gv = half ? v1x : v1;
      float ov = half ? v1  : v1x;
      float cn = fsig(fv) * cc[r] + fsig(iv) * ftanh(gv);
      cc[r] = cn;
      float hv = fsig(ov) * ftanh(cn);
      if (half == 0) {
        int row = (r & 3) + 8 * (r >> 2) + 4 * khalf;
        unsigned short hbits = __builtin_bit_cast(unsigned short, (bf16)hv);
        HSTORE2(hdst + row * 16 + col32, hbits);
      }
    }
  };

  // L0 x-projection for step (trow+1): acc = bias + inp[:,trow,:] @ W0
  auto xw0 = [&](int trow, f32x16& A0, f32x16& A1) {
#pragma unroll
    for (int r = 0; r < 16; ++r) { A0[r] = bE0a; A1[r] = bE0b; }
    const float* p = inp + ((size_t)rowA * 128 + trow) * 64 + khalf * 8;
#pragma unroll
    for (int ks = 0; ks < 4; ++ks) {
      bf16x8 bg0 = *reinterpret_cast<const bf16x8*>(rX0e + (size_t)ks * 512 + lane * 8);
      bf16x8 bg1 = *reinterpret_cast<const bf16x8*>(rX0e + (size_t)(4 + ks) * 512 + lane * 8);
      const float* pp = p + ks * 16;
      bf16x8 af;
#pragma unroll
      for (int j = 0; j < 8; ++j) af[j] = (bf16)pp[j];
      A0 = __builtin_amdgcn_mfma_f32_32x32x16_bf16(af, bg0, A0, 0, 0, 0);
      A1 = __builtin_amdgcn_mfma_f32_32x32x16_bf16(af, bg1, A1, 0, 0, 0);
    }
  };

  // ================= prologue =================
  load_lds(rU0e, LDS_U0);
  load_lds(rU1e, LDS_U1);

  f32x16 xa0, xa1, ya0, ya1;
  xw0(0, xa0, xa1);
#pragma unroll
  for (int r = 0; r < 16; ++r) { ya0[r] = bE1a; ya1[r] = bE1b; }
  stageW(0, LDS_WP0);
  stageW(1, LDS_WP1);

  // ================= pipelined encoder ticks =================
#pragma unroll 1
  for (int t = 1; t <= 129; ++t) {
    const char* hp0 = (const char*)hb + (size_t)((t - 1) & 1) * 262144
                      + (size_t)g * 32768 + (lane & 31) * 32 + khalf * 16;
    const char* hp1 = (const char*)hb + 524288 + (size_t)(t & 1) * 262144
                      + (size_t)g * 32768 + (lane & 31) * 32 + khalf * 16;

    // h0(t-1) ready?  (W ping batches 0,1 already staged; poll drains them)
    if (lane < 32) {
      while (__hip_atomic_load(flag0 + lane, __ATOMIC_RELAXED, __HIP_MEMORY_SCOPE_AGENT)
             < (unsigned)(t - 1)) { }
    }
#pragma unroll
    for (int i = 0; i < 16; ++i) HLOAD16(hreg[i], hp0 + i * 1024);

    // fused L0-rec + L1-x over k=512 (4 batches of 8 k-slices)
    WAIT_VM(8);  SCHED0();
    fbatch(0, LDS_WP0, xa0, xa1, ya0, ya1);
    WAIT_LGKM0();
    stageW(2, LDS_WP0);
#pragma unroll
    for (int i = 0; i < 8; ++i) HLOAD16(hreg[i], hp0 + (16 + i) * 1024);
    WAIT_VM(24); SCHED0();
    fbatch(1, LDS_WP1, xa0, xa1, ya0, ya1);
    WAIT_LGKM0();
    stageW(3, LDS_WP1);
#pragma unroll
    for (int i = 0; i < 8; ++i) HLOAD16(hreg[8 + i], hp0 + (24 + i) * 1024);
    WAIT_VM(24); SCHED0();
    fbatch(2, LDS_WP0, xa0, xa1, ya0, ya1);
    WAIT_VM(0);  SCHED0();
    fbatch(3, LDS_WP1, xa0, xa1, ya0, ya1);

    // h1(t-2) ready? issue its loads so they fly under the L0 gates
    if (t >= 2) {
      if (lane < 32) {
        while (__hip_atomic_load(flag1 + lane, __ATOMIC_RELAXED, __HIP_MEMORY_SCOPE_AGENT)
               < (unsigned)(t - 2)) { }
      }
#pragma unroll
      for (int i = 0; i < 16; ++i) HLOAD16(hreg[i], hp1 + i * 1024);
    }

    // L0 gates + h0(t) publish (flag0 mid-tick: gives consumers a head start)
    bf16* h0dst = hb + (size_t)(t & 1) * 131072 + (size_t)g * 16384 + (size_t)nc * 512;
    gates(xa0, xa1, c0, h0dst);
    WAIT_VM(0);  SCHED0();
    if (lane == 0)
      __hip_atomic_store(flag0 + nc, (unsigned)t, __ATOMIC_RELAXED, __HIP_MEMORY_SCOPE_AGENT);

    // L1 recurrence + gates + publish
    if (t >= 2) {
      ubatch(0, LDS_U1, ya0, ya1);
#pragma unroll
      for (int i = 0; i < 8; ++i) HLOAD16(hreg[i], hp1 + (16 + i) * 1024);
      ubatch(1, LDS_U1, ya0, ya1);
#pragma unroll
      for (int i = 0; i < 8; ++i) HLOAD16(hreg[8 + i], hp1 + (24 + i) * 1024);
      WAIT_VM(8); SCHED0();
      ubatch(2, LDS_U1, ya0, ya1);
      WAIT_VM(0); SCHED0();
      ubatch(3, LDS_U1, ya0, ya1);

      bf16* h1dst = hb + 262144 + (size_t)((t - 1) & 1) * 131072
                    + (size_t)g * 16384 + (size_t)nc * 512;
      gates(ya0, ya1, c1, h1dst);
      WAIT_VM(0);
      if (lane == 0)
        __hip_atomic_store(flag1 + nc, (unsigned)(t - 1), __ATOMIC_RELAXED, __HIP_MEMORY_SCOPE_AGENT);
    }

    // next tick's L0 x-projection + restage W ping batches 0,1
    if (t <= 128) {
      xw0(t < 128 ? t : 127, xa0, xa1);
#pragma unroll
      for (int r = 0; r < 16; ++r) { ya0[r] = bE1a; ya1[r] = bE1b; }
      WAIT_LGKM0();
      stageW(0, LDS_WP0);
      stageW(1, LDS_WP1);
    }
  }

  // ================= decoder layer 0 (tick 130) =================
  f32x16 da0, da1;
  {
    load_lds(rW + EO_DU0 + (size_t)nc * 32768, LDS_U0);
#pragma unroll
    for (int r = 0; r < 16; ++r) { da0[r] = bD0a; da1[r] = bD0b; }
    const bf16* rXd = rW + EO_DW0 + (size_t)nc * 1024;
    bf16x8 bg0 = *reinterpret_cast<const bf16x8*>(rXd + lane * 8);
    bf16x8 bg1 = *reinterpret_cast<const bf16x8*>(rXd + 512 + lane * 8);
    const float* p = inp + ((size_t)rowA * 128 + 127) * 64 + khalf * 8;  // inp[:,-1,:16]
    bf16x8 af;
#pragma unroll
    for (int j = 0; j < 8; ++j) af[j] = (bf16)p[j];
    da0 = __builtin_amdgcn_mfma_f32_32x32x16_bf16(af, bg0, da0, 0, 0, 0);
    da1 = __builtin_amdgcn_mfma_f32_32x32x16_bf16(af, bg1, da1, 0, 0, 0);

    if (lane < 32) {
      while (__hip_atomic_load(flag1 + lane, __ATOMIC_RELAXED, __HIP_MEMORY_SCOPE_AGENT) < 128u) { }
    }
    // h1(128) lives in layer1/buf0
    recgemm((const char*)hb + 524288 + (size_t)g * 32768 + (lane & 31) * 32 + khalf * 16,
            LDS_U0, da0, da1);
    bf16* d0dst = hb + (size_t)g * 16384 + (size_t)nc * 512;   // layer0/buf0
    gates(da0, da1, c1, d0dst);
    WAIT_VM(0);
    if (lane == 0)
      __hip_atomic_store(flag0 + nc, 130u, __ATOMIC_RELAXED, __HIP_MEMORY_SCOPE_AGENT);
  }

  // ================= decoder layer 1 (tick 131): z = d0 @ (dW1+dU1) + b ==========
  {
    load_lds(rW + EO_DU1 + (size_t)nc * 32768, LDS_U0);
#pragma unroll
    for (int r = 0; r < 16; ++r) { da0[r] = bD1a; da1[r] = bD1b; }
    if (lane < 32) {
      while (__hip_atomic_load(flag0 + lane, __ATOMIC_RELAXED, __HIP_MEMORY_SCOPE_AGENT) < 130u) { }
    }
    recgemm((const char*)hb + (size_t)g * 32768 + (lane & 31) * 32 + khalf * 16,
            LDS_U0, da0, da1);
    bf16* d1dst = hb + 262144 + (size_t)g * 16384 + (size_t)nc * 512;  // layer1/buf0
    gates(da0, da1, c1, d1dst);
  }

  // cross-group visibility for FC (wg reads batch row wgid, produced by another group)
  dbarrier();

  // ================= FC + tile(48) : wg handles batch row = wgid =================
  {
    // d1 row=wgid in block layout (layer1/buf0): group wgid>>5, producer lane>>1
    const char* dp = (const char*)hb + 524288
                     + (size_t)(wgid >> 5) * 32768 + (lane >> 1) * 1024
                     + (wgid & 31) * 32 + (lane & 1) * 16;
    u32x4 dreg;
    HLOAD16(dreg, dp);
    WAIT_VM(0);
    SCHED0();
    bf16x8 xv = __builtin_bit_cast(bf16x8, dreg);
    float part[16];
#pragma unroll
    for (int o = 0; o < 16; ++o) part[o] = 0.f;
#pragma unroll
    for (int j = 0; j < 8; ++j) {
      float x = (float)xv[j];
      const float* wrow = fcW + (size_t)(lane * 8 + j) * 16;
#pragma unroll
      for (int o = 0; o < 16; ++o) part[o] = fmaf(x, wrow[o], part[o]);
    }
    __syncthreads();
    float* fl = reinterpret_cast<float*>(smem);
#pragma unroll
    for (int o = 0; o < 16; ++o) fl[lane * 17 + o] = part[o];
    __syncthreads();
    if (lane < 16) {
      float sum = fcb[lane];
      for (int l = 0; l < 64; ++l) sum += fl[l * 17 + lane];
      fl[64 * 17 + lane] = sum;
    }
    __syncthreads();
    const int quad = lane >> 4;
    const float val = fl[64 * 17 + (lane & 15)];
    float* orow = out + (size_t)wgid * 768;
#pragma unroll
    for (int rep = 0; rep < 12; ++rep) {
      orow[(rep * 4 + quad) * 16 + (lane & 15)] = val;
    }
  }
}

// ---------------- launch ----------------
extern "C" void kernel_launch(void* const* d_in, const int* in_sizes, int n_in,
                              void* d_out, int out_size, void* d_ws, size_t ws_size,
                              hipStream_t stream) {
  (void)in_sizes; (void)n_in; (void)out_size; (void)ws_size;
  const float* inp = (const float*)d_in[0];
  // d_in[1] = future_seq_len (48, hardcoded)
  const float* eW0 = (const float*)d_in[2];
  const float* eU0 = (const float*)d_in[3];
  const float* eb0 = (const float*)d_in[4];
  const float* eW1 = (const float*)d_in[5];
  const float* eU1 = (const float*)d_in[6];
  const float* eb1 = (const float*)d_in[7];
  const float* dW0 = (const float*)d_in[8];
  const float* dU0 = (const float*)d_in[9];
  const float* db0 = (const float*)d_in[10];
  const float* dW1 = (const float*)d_in[11];
  const float* dU1 = (const float*)d_in[12];
  const float* db1 = (const float*)d_in[13];
  const float* fcW = (const float*)d_in[14];
  const float* fcb = (const float*)d_in[15];
  unsigned char* ws = (unsigned char*)d_ws;
  float* out = (float*)d_out;

  static bool attr_set = false;
  if (!attr_set) {
    (void)hipFuncSetAttribute(reinterpret_cast<const void*>(lstm_main),
                              hipFuncAttributeMaxDynamicSharedMemorySize, LDS_TOTAL);
    attr_set = true;
  }

  // zero h exchange buffers + both flag arrays + device counter (contiguous)
  hipMemsetAsync(ws + OFF_HB, 0, HB_BYTES + 1024 + 1024 + 64, stream);

  lstm_main<<<dim3(256), dim3(64), LDS_TOTAL, stream>>>(
      inp, eW0, eU0, eb0, eW1, eU1, eb1, dW0, dU0, db0, dW1, dU1, db1,
      fcW, fcb, ws, out);
}

// Round 5
// 1899.692 us; speedup vs baseline: 1.3154x; 1.0042x over previous
//
#include <hip/hip_runtime.h>

typedef __bf16 bf16;
typedef __bf16 bf16x8 __attribute__((ext_vector_type(8)));
typedef float  f32x16 __attribute__((ext_vector_type(16)));
typedef unsigned int u32;
typedef unsigned int u32x4 __attribute__((ext_vector_type(4)));

// ---------------- ws layout (bytes) ----------------
#define OFF_RW      0ull                 // rearranged weights, bf16 (12910592 B)
// h exchange: [layer2][buf2][group8][producer32][row32][col16] bf16 = 1 MB
#define OFF_HB      12910592ull
#define HB_BYTES    1048576ull
#define OFF_FLAG0   13959168ull          // 8 groups x 32 producer flags (u32)
#define OFF_FLAG1   13960192ull
#define OFF_DCTR    13961216ull          // device barrier counter (64 B)

// elem offsets into rW (bf16 elems); K-prefix {0,64,576,1088,1600,1616,2128,2640}
#define EO_W0   0
#define EO_U0   131072
#define EO_W1   1179648
#define EO_U1   2228224
#define EO_DW0  3276800
#define EO_DU0  3309568
#define EO_DW1  4358144
#define EO_DU1  5406720   // holds (dW1 + dU1) combined (dec1: x == h_init)

// LDS layout (dynamic 160 KB)
#define LDS_U0    0u
#define LDS_U1    65536u
#define LDS_WP0   131072u
#define LDS_WP1   147456u
#define LDS_TOTAL 163840

// ---------------- activations ----------------
__device__ __forceinline__ float fsig(float x) {
  x = fminf(fmaxf(x, -30.f), 30.f);
  float e = __builtin_amdgcn_exp2f(x * -1.4426950408889634f);
  return __builtin_amdgcn_rcpf(1.0f + e);
}
__device__ __forceinline__ float ftanh(float x) {
  x = fminf(fmaxf(x, -15.f), 15.f);
  float e = __builtin_amdgcn_exp2f(x * -2.8853900817779268f);
  return (1.0f - e) * __builtin_amdgcn_rcpf(1.0f + e);
}

// sc1 (agent-coherent / LLC) memory ops
#define HLOAD16(dst, addr) \
  asm volatile("global_load_dwordx4 %0, %1, off sc1" : "=v"(dst) : "v"(addr) : "memory")
#define HSTORE2(addr, val) \
  asm volatile("global_store_short %0, %1, off sc1" :: "v"(addr), "v"(val) : "memory")
#define HSTORE16(addr, val) \
  asm volatile("global_store_dwordx4 %0, %1, off sc1" :: "v"(addr), "v"(val) : "memory")
#define WAIT_VM(n) asm volatile("s_waitcnt vmcnt(" #n ")" ::: "memory")
#define WAIT_LGKM0() asm volatile("s_waitcnt lgkmcnt(0)" ::: "memory")
#define SCHED0() __builtin_amdgcn_sched_barrier(0)

typedef const __attribute__((address_space(1))) u32* as1_u32p;
typedef __attribute__((address_space(3))) u32* as3_u32p;
// global -> LDS direct (width 16B/lane), dest = uniform base + lane*16
#define GLL16(gsrc, ldsoff) \
  __builtin_amdgcn_global_load_lds((as1_u32p)(const void*)(gsrc), \
                                   (as3_u32p)(void*)(smem + (ldsoff)), 16, 0, 0)

// ---------------- main persistent kernel ----------------
// grid 256 wgs x 64 thr; wg -> (group g = blk&7 [32 batch rows], nc = blk>>3 [16 h-cols])
// Pipelined ticks t=1..129: L0 step t  +  L1 step t-1 (L1 trails by 1).
// flag0 published immediately after L0 gates (shortest 1-tick loop); xw0 overlaps
// the h1 exchange loads. NOTE: dummy xw0 at t=128 must clamp to row 127 (OOB fix).
__global__ void __launch_bounds__(64, 1)
lstm_main(const float* __restrict__ inp,
          const float* __restrict__ eW0, const float* __restrict__ eU0, const float* __restrict__ eb0,
          const float* __restrict__ eW1, const float* __restrict__ eU1, const float* __restrict__ eb1,
          const float* __restrict__ dW0, const float* __restrict__ dU0, const float* __restrict__ db0,
          const float* __restrict__ dW1, const float* __restrict__ dU1, const float* __restrict__ db1,
          const float* __restrict__ fcW, const float* __restrict__ fcb,
          unsigned char* __restrict__ ws, float* __restrict__ out)
{
  extern __shared__ __align__(16) unsigned char smem[];

  const int wgid = blockIdx.x;
  const int g    = wgid & 7;
  const int nc   = wgid >> 3;
  const int lane = threadIdx.x;
  const int rowbase = g * 32;
  const int col32 = lane & 31;
  const int khalf = lane >> 5;
  const int half  = col32 >> 4;
  const int rowA  = rowbase + col32;

  const bf16* rW = reinterpret_cast<const bf16*>(ws + OFF_RW);
  bf16* hb  = reinterpret_cast<bf16*>(ws + OFF_HB);
  unsigned* flag0 = reinterpret_cast<unsigned*>(ws + OFF_FLAG0) + g * 32;
  unsigned* flag1 = reinterpret_cast<unsigned*>(ws + OFF_FLAG1) + g * 32;
  unsigned* dctr  = reinterpret_cast<unsigned*>(ws + OFF_DCTR);

  unsigned depoch = 0;
  auto dbarrier = [&]() {
    depoch++;
    WAIT_VM(0);
    if (lane == 0) __hip_atomic_fetch_add(dctr, 1u, __ATOMIC_RELAXED, __HIP_MEMORY_SCOPE_AGENT);
    const unsigned tgt = depoch * 256u;
    while (__hip_atomic_load(dctr, __ATOMIC_RELAXED, __HIP_MEMORY_SCOPE_AGENT) < tgt)
      __builtin_amdgcn_s_sleep(1);
  };

  // ================= inline prep: weights -> MFMA B-fragment order (sc1 stores) ====
  {
    const int Ks[8]    = {64, 512, 512, 512, 16, 512, 512, 512};
    const int pref[8]  = {0, 64, 576, 1088, 1600, 1616, 2128, 2640};
    const float* srcs[8] = {eW0, eU0, eW1, eU1, dW0, dU0, dW1, dU1};
    bf16* rWw = reinterpret_cast<bf16*>(ws + OFF_RW);
    for (int base = 0; base < 3152; base += 64) {
      if (base + lane < 3152) {
        unsigned uid = (unsigned)wgid * 3152u + (unsigned)(base + lane);
        int m = 0;
#pragma unroll
        for (int i = 1; i < 8; ++i) if (uid >= (unsigned)pref[i] * 256u) m = i;
        unsigned local = uid - (unsigned)pref[m] * 256u;
        const int K = Ks[m];
        const unsigned perNC   = (unsigned)K * 8u;
        const unsigned ncb     = local / perNC;
        const unsigned r0      = local % perNC;
        const unsigned perTile = perNC >> 1;
        const unsigned ntile   = r0 / perTile;
        const unsigned r1      = r0 % perTile;
        const unsigned kstep   = r1 >> 6;
        const unsigned ln      = r1 & 63u;
        const unsigned c32     = ln & 31u;
        const unsigned gate    = ntile * 2u + (c32 >> 4);
        const unsigned zcol    = gate * 512u + ncb * 16u + (c32 & 15u);
        const unsigned kb      = kstep * 16u + (ln >> 5) * 8u;
        const float* s = srcs[m];
        bf16x8 v;
#pragma unroll
        for (int j = 0; j < 8; ++j) {
          float vj = s[(size_t)(kb + j) * 2048u + zcol];
          if (m == 7) vj += dW1[(size_t)(kb + j) * 2048u + zcol];  // dec1 combined W+U
          v[j] = (bf16)vj;
        }
        u32x4 bits = __builtin_bit_cast(u32x4, v);
        HSTORE16(rWw + (size_t)uid * 8, bits);
      }
    }
  }
  dbarrier();
  __builtin_amdgcn_fence(__ATOMIC_ACQUIRE, "agent");  // one-time: purge stale L1/L2

  // bias registers (gate pair [i|f] -> a, [g|o] -> b)
  const int bcol = nc * 16 + (col32 & 15);
  const int bg_  = col32 >> 4;
  const float bE0a = eb0[bg_ * 512 + bcol], bE0b = eb0[(2 + bg_) * 512 + bcol];
  const float bE1a = eb1[bg_ * 512 + bcol], bE1b = eb1[(2 + bg_) * 512 + bcol];
  const float bD0a = db0[bg_ * 512 + bcol], bD0b = db0[(2 + bg_) * 512 + bcol];
  const float bD1a = db1[bg_ * 512 + bcol], bD1b = db1[(2 + bg_) * 512 + bcol];

  float c0[16], c1[16];
#pragma unroll
  for (int i = 0; i < 16; ++i) { c0[i] = 0.f; c1[i] = 0.f; }

  const bf16* rU0e = rW + EO_U0 + (size_t)nc * 32768;
  const bf16* rU1e = rW + EO_U1 + (size_t)nc * 32768;
  const bf16* rX0e = rW + EO_W0 + (size_t)nc * 4096;
  const bf16* rX1e = rW + EO_W1 + (size_t)nc * 32768;

  u32x4 hreg[16];

  auto load_lds = [&](const bf16* src, u32 off) {
#pragma unroll 8
    for (int i = 0; i < 64; ++i) {
      *reinterpret_cast<bf16x8*>(smem + off + (i * 64 + lane) * 16) =
        *reinterpret_cast<const bf16x8*>(src + (size_t)(i * 64 + lane) * 8);
    }
    __syncthreads();
  };

  // stage W1 batch b (8 k-slices, both gate tiles) -> LDS ping at ldsoff (16 KB)
  auto stageW = [&](int b, u32 ldsoff) {
    const char* src0 = (const char*)rX1e + (size_t)b * 8192 + lane * 16;           // bg0
    const char* src1 = (const char*)rX1e + 32768 + (size_t)b * 8192 + lane * 16;   // bg1
#pragma unroll
    for (int j = 0; j < 8; ++j) {
      GLL16(src0 + j * 1024, ldsoff + j * 1024);
      GLL16(src1 + j * 1024, ldsoff + 8192 + j * 1024);
    }
  };

  // fused batch: L0 rec (U0 from LDS) + L1 x (W1 from LDS ping), shared A-frags
  auto fbatch = [&](int b, u32 wp, f32x16& A0, f32x16& A1, f32x16& D0, f32x16& D1) {
#pragma unroll
    for (int i = 0; i < 8; ++i) {
      const int ks = b * 8 + i;
      bf16x8 af  = __builtin_bit_cast(bf16x8, hreg[(b & 1) * 8 + i]);
      bf16x8 bl0 = *reinterpret_cast<const bf16x8*>(smem + LDS_U0 + (ks * 64 + lane) * 16);
      bf16x8 bl1 = *reinterpret_cast<const bf16x8*>(smem + LDS_U0 + 32768 + (ks * 64 + lane) * 16);
      bf16x8 bw0 = *reinterpret_cast<const bf16x8*>(smem + wp + i * 1024 + lane * 16);
      bf16x8 bw1 = *reinterpret_cast<const bf16x8*>(smem + wp + 8192 + i * 1024 + lane * 16);
      A0 = __builtin_amdgcn_mfma_f32_32x32x16_bf16(af, bl0, A0, 0, 0, 0);
      A1 = __builtin_amdgcn_mfma_f32_32x32x16_bf16(af, bl1, A1, 0, 0, 0);
      D0 = __builtin_amdgcn_mfma_f32_32x32x16_bf16(af, bw0, D0, 0, 0, 0);
      D1 = __builtin_amdgcn_mfma_f32_32x32x16_bf16(af, bw1, D1, 0, 0, 0);
    }
  };

  // plain recurrent batch vs LDS U at uoff
  auto ubatch = [&](int b, u32 uoff, f32x16& A0, f32x16& A1) {
#pragma unroll
    for (int i = 0; i < 8; ++i) {
      const int ks = b * 8 + i;
      bf16x8 af  = __builtin_bit_cast(bf16x8, hreg[(b & 1) * 8 + i]);
      bf16x8 bl0 = *reinterpret_cast<const bf16x8*>(smem + uoff + (ks * 64 + lane) * 16);
      bf16x8 bl1 = *reinterpret_cast<const bf16x8*>(smem + uoff + 32768 + (ks * 64 + lane) * 16);
      A0 = __builtin_amdgcn_mfma_f32_32x32x16_bf16(af, bl0, A0, 0, 0, 0);
      A1 = __builtin_amdgcn_mfma_f32_32x32x16_bf16(af, bl1, A1, 0, 0, 0);
    }
  };

  // full h-block GEMM with its own pipelined loads (decoder steps)
  auto recgemm = [&](const char* hp, u32 uoff, f32x16& A0, f32x16& A1) {
#pragma unroll
    for (int i = 0; i < 16; ++i) HLOAD16(hreg[i], hp + i * 1024);
#pragma unroll
    for (int b = 0; b < 4; ++b) {
      if (b < 3) { WAIT_VM(8); } else { WAIT_VM(0); }
      SCHED0();
      ubatch(b, uoff, A0, A1);
      if (b < 2) {
#pragma unroll
        for (int i = 0; i < 8; ++i) HLOAD16(hreg[(b & 1) * 8 + i], hp + (16 + b * 8 + i) * 1024);
      }
    }
  };

  // gates: A0=[i|f] cols, A1=[g|o] cols; partner via shfl_xor 16; h slice -> hdst
  auto gates = [&](f32x16& A0, f32x16& A1, float* cc, bf16* hdst) {
#pragma unroll
    for (int r = 0; r < 16; ++r) {
      float v0 = A0[r], v1 = A1[r];
      float v0x = __shfl_xor(v0, 16, 64);
      float v1x = __shfl_xor(v1, 16, 64);
      float iv = half ? v0x : v0;
      float fv = half ? v0  : v0x;
      float gv = half ? v1x : v1;
      float ov = half ? v1  : v1x;
      float cn = fsig(fv) * cc[r] + fsig(iv) * ftanh(gv);
      cc[r] = cn;
      float hv = fsig(ov) * ftanh(cn);
      if (half == 0) {
        int row = (r & 3) + 8 * (r >> 2) + 4 * khalf;
        unsigned short hbits = __builtin_bit_cast(unsigned short, (bf16)hv);
        HSTORE2(hdst + row * 16 + col32, hbits);
      }
    }
  };

  // L0 x-projection for step (trow+1): acc = bias + inp[:,trow,:] @ W0
  auto xw0 = [&](int trow, f32x16& A0, f32x16& A1) {
#pragma unroll
    for (int r = 0; r < 16; ++r) { A0[r] = bE0a; A1[r] = bE0b; }
    const float* p = inp + ((size_t)rowA * 128 + trow) * 64 + khalf * 8;
#pragma unroll
    for (int ks = 0; ks < 4; ++ks) {
      bf16x8 bg0 = *reinterpret_cast<const bf16x8*>(rX0e + (size_t)ks * 512 + lane * 8);
      bf16x8 bg1 = *reinterpret_cast<const bf16x8*>(rX0e + (size_t)(4 + ks) * 512 + lane * 8);
      const float* pp = p + ks * 16;
      bf16x8 af;
#pragma unroll
      for (int j = 0; j < 8; ++j) af[j] = (bf16)pp[j];
      A0 = __builtin_amdgcn_mfma_f32_32x32x16_bf16(af, bg0, A0, 0, 0, 0);
      A1 = __builtin_amdgcn_mfma_f32_32x32x16_bf16(af, bg1, A1, 0, 0, 0);
    }
  };

  // ================= prologue =================
  load_lds(rU0e, LDS_U0);
  load_lds(rU1e, LDS_U1);

  f32x16 xa0, xa1, ya0, ya1;
  xw0(0, xa0, xa1);
#pragma unroll
  for (int r = 0; r < 16; ++r) { ya0[r] = bE1a; ya1[r] = bE1b; }
  stageW(0, LDS_WP0);
  stageW(1, LDS_WP1);

  // ================= pipelined encoder ticks =================
#pragma unroll 1
  for (int t = 1; t <= 129; ++t) {
    const char* hp0 = (const char*)hb + (size_t)((t - 1) & 1) * 262144
                      + (size_t)g * 32768 + (lane & 31) * 32 + khalf * 16;
    const char* hp1 = (const char*)hb + 524288 + (size_t)(t & 1) * 262144
                      + (size_t)g * 32768 + (lane & 31) * 32 + khalf * 16;

    // h0(t-1) ready?
    if (lane < 32) {
      while (__hip_atomic_load(flag0 + lane, __ATOMIC_RELAXED, __HIP_MEMORY_SCOPE_AGENT)
             < (unsigned)(t - 1)) { }
    }
#pragma unroll
    for (int i = 0; i < 16; ++i) HLOAD16(hreg[i], hp0 + i * 1024);

    // fused L0-rec + L1-x over k=512 (4 batches of 8 k-slices)
    WAIT_VM(8);  SCHED0();
    fbatch(0, LDS_WP0, xa0, xa1, ya0, ya1);
    WAIT_LGKM0();
    stageW(2, LDS_WP0);
#pragma unroll
    for (int i = 0; i < 8; ++i) HLOAD16(hreg[i], hp0 + (16 + i) * 1024);
    WAIT_VM(24); SCHED0();
    fbatch(1, LDS_WP1, xa0, xa1, ya0, ya1);
    WAIT_LGKM0();
    stageW(3, LDS_WP1);
#pragma unroll
    for (int i = 0; i < 8; ++i) HLOAD16(hreg[8 + i], hp0 + (24 + i) * 1024);
    WAIT_VM(24); SCHED0();
    fbatch(2, LDS_WP0, xa0, xa1, ya0, ya1);
    WAIT_VM(0);  SCHED0();
    fbatch(3, LDS_WP1, xa0, xa1, ya0, ya1);

    // L0 gates + publish FIRST: flag0 is the 1-tick loop everyone spins on.
    // (Drain covers only the h0 gate stores now, not freshly-issued h1 loads.)
    bf16* h0dst = hb + (size_t)(t & 1) * 131072 + (size_t)g * 16384 + (size_t)nc * 512;
    gates(xa0, xa1, c0, h0dst);
    WAIT_VM(0);  SCHED0();
    if (lane == 0)
      __hip_atomic_store(flag0 + nc, (unsigned)t, __ATOMIC_RELAXED, __HIP_MEMORY_SCOPE_AGENT);

    // L1 phase: poll h1(t-2), overlap its loads with next tick's xw0
    if (t >= 2) {
      if (lane < 32) {
        while (__hip_atomic_load(flag1 + lane, __ATOMIC_RELAXED, __HIP_MEMORY_SCOPE_AGENT)
               < (unsigned)(t - 2)) { }
      }
#pragma unroll
      for (int i = 0; i < 16; ++i) HLOAD16(hreg[i], hp1 + i * 1024);
      // independent MFMA fills h1 LLC latency; CLAMP row (t=128 is a dummy
      // projection consumed only by the discarded tick-129 L0 step — row 128
      // would be out of bounds and page-faults).
      if (t <= 128) xw0(t < 128 ? t : 127, xa0, xa1);
      WAIT_VM(8); SCHED0();
      ubatch(0, LDS_U1, ya0, ya1);
#pragma unroll
      for (int i = 0; i < 8; ++i) HLOAD16(hreg[i], hp1 + (16 + i) * 1024);
      WAIT_VM(8); SCHED0();
      ubatch(1, LDS_U1, ya0, ya1);
#pragma unroll
      for (int i = 0; i < 8; ++i) HLOAD16(hreg[8 + i], hp1 + (24 + i) * 1024);
      WAIT_VM(8); SCHED0();
      ubatch(2, LDS_U1, ya0, ya1);
      WAIT_VM(0); SCHED0();
      ubatch(3, LDS_U1, ya0, ya1);

      bf16* h1dst = hb + 262144 + (size_t)((t - 1) & 1) * 131072
                    + (size_t)g * 16384 + (size_t)nc * 512;
      gates(ya0, ya1, c1, h1dst);
      WAIT_VM(0);
      if (lane == 0)
        __hip_atomic_store(flag1 + nc, (unsigned)(t - 1), __ATOMIC_RELAXED, __HIP_MEMORY_SCOPE_AGENT);
    } else {
      xw0(1, xa0, xa1);                   // t==1: no L1 phase yet
    }

    // reset ya + restage W ping batches 0,1 for next tick
    if (t <= 128) {
#pragma unroll
      for (int r = 0; r < 16; ++r) { ya0[r] = bE1a; ya1[r] = bE1b; }
      WAIT_LGKM0();
      stageW(0, LDS_WP0);
      stageW(1, LDS_WP1);
    }
  }

  // ================= decoder layer 0 (tick 130) =================
  f32x16 da0, da1;
  {
    load_lds(rW + EO_DU0 + (size_t)nc * 32768, LDS_U0);
#pragma unroll
    for (int r = 0; r < 16; ++r) { da0[r] = bD0a; da1[r] = bD0b; }
    const bf16* rXd = rW + EO_DW0 + (size_t)nc * 1024;
    bf16x8 bg0 = *reinterpret_cast<const bf16x8*>(rXd + lane * 8);
    bf16x8 bg1 = *reinterpret_cast<const bf16x8*>(rXd + 512 + lane * 8);
    const float* p = inp + ((size_t)rowA * 128 + 127) * 64 + khalf * 8;  // inp[:,-1,:16]
    bf16x8 af;
#pragma unroll
    for (int j = 0; j < 8; ++j) af[j] = (bf16)p[j];
    da0 = __builtin_amdgcn_mfma_f32_32x32x16_bf16(af, bg0, da0, 0, 0, 0);
    da1 = __builtin_amdgcn_mfma_f32_32x32x16_bf16(af, bg1, da1, 0, 0, 0);

    if (lane < 32) {
      while (__hip_atomic_load(flag1 + lane, __ATOMIC_RELAXED, __HIP_MEMORY_SCOPE_AGENT) < 128u) { }
    }
    // h1(128) lives in layer1/buf0
    recgemm((const char*)hb + 524288 + (size_t)g * 32768 + (lane & 31) * 32 + khalf * 16,
            LDS_U0, da0, da1);
    bf16* d0dst = hb + (size_t)g * 16384 + (size_t)nc * 512;   // layer0/buf0
    gates(da0, da1, c1, d0dst);
    WAIT_VM(0);
    if (lane == 0)
      __hip_atomic_store(flag0 + nc, 130u, __ATOMIC_RELAXED, __HIP_MEMORY_SCOPE_AGENT);
  }

  // ================= decoder layer 1 (tick 131): z = d0 @ (dW1+dU1) + b ==========
  {
    load_lds(rW + EO_DU1 + (size_t)nc * 32768, LDS_U0);
#pragma unroll
    for (int r = 0; r < 16; ++r) { da0[r] = bD1a; da1[r] = bD1b; }
    if (lane < 32) {
      while (__hip_atomic_load(flag0 + lane, __ATOMIC_RELAXED, __HIP_MEMORY_SCOPE_AGENT) < 130u) { }
    }
    recgemm((const char*)hb + (size_t)g * 32768 + (lane & 31) * 32 + khalf * 16,
            LDS_U0, da0, da1);
    bf16* d1dst = hb + 262144 + (size_t)g * 16384 + (size_t)nc * 512;  // layer1/buf0
    gates(da0, da1, c1, d1dst);
  }

  // cross-group visibility for FC (wg reads batch row wgid, produced by another group)
  dbarrier();

  // ================= FC + tile(48) : wg handles batch row = wgid =================
  {
    // d1 row=wgid in block layout (layer1/buf0): group wgid>>5, producer lane>>1
    const char* dp = (const char*)hb + 524288
                     + (size_t)(wgid >> 5) * 32768 + (lane >> 1) * 1024
                     + (wgid & 31) * 32 + (lane & 1) * 16;
    u32x4 dreg;
    HLOAD16(dreg, dp);
    WAIT_VM(0);
    SCHED0();
    bf16x8 xv = __builtin_bit_cast(bf16x8, dreg);
    float part[16];
#pragma unroll
    for (int o = 0; o < 16; ++o) part[o] = 0.f;
#pragma unroll
    for (int j = 0; j < 8; ++j) {
      float x = (float)xv[j];
      const float* wrow = fcW + (size_t)(lane * 8 + j) * 16;
#pragma unroll
      for (int o = 0; o < 16; ++o) part[o] = fmaf(x, wrow[o], part[o]);
    }
    __syncthreads();
    float* fl = reinterpret_cast<float*>(smem);
#pragma unroll
    for (int o = 0; o < 16; ++o) fl[lane * 17 + o] = part[o];
    __syncthreads();
    if (lane < 16) {
      float sum = fcb[lane];
      for (int l = 0; l < 64; ++l) sum += fl[l * 17 + lane];
      fl[64 * 17 + lane] = sum;
    }
    __syncthreads();
    const int quad = lane >> 4;
    const float val = fl[64 * 17 + (lane & 15)];
    float* orow = out + (size_t)wgid * 768;
#pragma unroll
    for (int rep = 0; rep < 12; ++rep) {
      orow[(rep * 4 + quad) * 16 + (lane & 15)] = val;
    }
  }
}

// ---------------- launch ----------------
extern "C" void kernel_launch(void* const* d_in, const int* in_sizes, int n_in,
                              void* d_out, int out_size, void* d_ws, size_t ws_size,
                              hipStream_t stream) {
  (void)in_sizes; (void)n_in; (void)out_size; (void)ws_size;
  const float* inp = (const float*)d_in[0];
  // d_in[1] = future_seq_len (48, hardcoded)
  const float* eW0 = (const float*)d_in[2];
  const float* eU0 = (const float*)d_in[3];
  const float* eb0 = (const float*)d_in[4];
  const float* eW1 = (const float*)d_in[5];
  const float* eU1 = (const float*)d_in[6];
  const float* eb1 = (const float*)d_in[7];
  const float* dW0 = (const float*)d_in[8];
  const float* dU0 = (const float*)d_in[9];
  const float* db0 = (const float*)d_in[10];
  const float* dW1 = (const float*)d_in[11];
  const float* dU1 = (const float*)d_in[12];
  const float* db1 = (const float*)d_in[13];
  const float* fcW = (const float*)d_in[14];
  const float* fcb = (const float*)d_in[15];
  unsigned char* ws = (unsigned char*)d_ws;
  float* out = (float*)d_out;

  static bool attr_set = false;
  if (!attr_set) {
    (void)hipFuncSetAttribute(reinterpret_cast<const void*>(lstm_main),
                              hipFuncAttributeMaxDynamicSharedMemorySize, LDS_TOTAL);
    attr_set = true;
  }

  // zero h exchange buffers + both flag arrays + device counter (contiguous)
  hipMemsetAsync(ws + OFF_HB, 0, HB_BYTES + 1024 + 1024 + 64, stream);

  lstm_main<<<dim3(256), dim3(64), LDS_TOTAL, stream>>>(
      inp, eW0, eU0, eb0, eW1, eU1, eb1, dW0, dU0, db0, dW1, dU1, db1,
      fcW, fcb, ws, out);
}